// Round 6
// baseline (88.060 us; speedup 1.0000x reference)
//
#include <hip/hip_runtime.h>

#define DIM   64
#define NROWS 65536
#define NCODE 1024
#define RPB   32                  // rows per block (2 row-tiles)
#define NBLK  (NROWS / RPB)       // 2048 blocks -> 8 available/CU

typedef float    f32x4 __attribute__((ext_vector_type(4)));
typedef _Float16 f16x8 __attribute__((ext_vector_type(8)));

union U4H { uint4 u; f16x8 h; };

// fp32 = h + r, h = RNE fp16; r exact (Sterbenz); l = RNE fp16 of r.
__device__ __forceinline__ void split2(float f, unsigned short& hb,
                                       unsigned short& lb) {
  _Float16 h = (_Float16)f;
  float r = f - (float)h;
  _Float16 l = (_Float16)r;
  hb = __builtin_bit_cast(unsigned short, h);
  lb = __builtin_bit_cast(unsigned short, l);
}
__device__ __forceinline__ uint4 pack8(const unsigned short* p) {
  return make_uint4((unsigned)p[0] | ((unsigned)p[1] << 16),
                    (unsigned)p[2] | ((unsigned)p[3] << 16),
                    (unsigned)p[4] | ((unsigned)p[5] << 16),
                    (unsigned)p[6] | ((unsigned)p[7] << 16));
}

// ---- pre-pass: e -> fp16 (h,l) B-fragments + e2/2; also zeroes loss ----
// tile gt (16 codes): 4 frags [kh0_h, kh0_l, kh1_h, kh1_l] x 512 shorts.
// Frag element (lane, i): code = gt*16 + (lane&15), k = kh*32 + (lane>>4)*8 + i
__global__ __launch_bounds__(256) void vq_esplit(const float* __restrict__ e,
                                                 unsigned short* __restrict__ eB,
                                                 float* __restrict__ e2h,
                                                 float* __restrict__ loss) {
  const int c = blockIdx.x * 256 + threadIdx.x;   // code 0..1023
  if (c == 0) *loss = 0.f;                        // stream-ordered before vq_main
  const int gt = c >> 4, cl = c & 15;
  float s = 0.f;
  #pragma unroll
  for (int kh = 0; kh < 2; ++kh) {
    #pragma unroll
    for (int g = 0; g < 4; ++g) {
      const float* ep = e + (size_t)c * DIM + kh * 32 + g * 8;
      float4 v0 = *(const float4*)ep;
      float4 v1 = *(const float4*)(ep + 4);
      float f[8] = {v0.x, v0.y, v0.z, v0.w, v1.x, v1.y, v1.z, v1.w};
      unsigned short hb[8], lb[8];
      #pragma unroll
      for (int j = 0; j < 8; ++j) {
        split2(f[j], hb[j], lb[j]);
        s = fmaf(f[j], f[j], s);
      }
      const size_t pos = (size_t)((g << 4) | cl) * 8;
      const size_t tb = (size_t)gt * 2048;
      *(uint4*)(eB + tb + (kh * 2 + 0) * 512 + pos) = pack8(hb);
      *(uint4*)(eB + tb + (kh * 2 + 1) * 512 + pos) = pack8(lb);
    }
  }
  e2h[c] = 0.5f * s;
}

// S' = dot(x,e) - e2/2 as one MFMA chain seeded with C = -e2/2.
#define VQ_STEP(CT, BUF, E2L)                                                      \
  {                                                                                \
    U4H u0, u1, u2, u3;                                                            \
    u0.u = BUF[0]; u1.u = BUF[1]; u2.u = BUF[2]; u3.u = BUF[3];                    \
    f16x8 b0h = u0.h, b0l = u1.h, b1h = u2.h, b1l = u3.h;                          \
    const int kk0 = w * 256 + (CT) * 16 + col;                                     \
    const float ne2 = -(E2L);                                                      \
    _Pragma("unroll")                                                              \
    for (int rt = 0; rt < 2; ++rt) {                                               \
      f32x4 c = {ne2, ne2, ne2, ne2};                                              \
      c = __builtin_amdgcn_mfma_f32_16x16x32_f16(a[rt][0][0], b0h, c, 0, 0, 0);    \
      c = __builtin_amdgcn_mfma_f32_16x16x32_f16(a[rt][0][1], b0h, c, 0, 0, 0);    \
      c = __builtin_amdgcn_mfma_f32_16x16x32_f16(a[rt][0][0], b0l, c, 0, 0, 0);    \
      c = __builtin_amdgcn_mfma_f32_16x16x32_f16(a[rt][1][0], b1h, c, 0, 0, 0);    \
      c = __builtin_amdgcn_mfma_f32_16x16x32_f16(a[rt][1][1], b1h, c, 0, 0, 0);    \
      c = __builtin_amdgcn_mfma_f32_16x16x32_f16(a[rt][1][0], b1l, c, 0, 0, 0);    \
      _Pragma("unroll")                                                            \
      for (int r = 0; r < 4; ++r) {                                                \
        if (c[r] > bestS[rt][r]) { bestS[rt][r] = c[r]; bestK[rt][r] = kk0; }      \
      }                                                                            \
    }                                                                              \
  }

// ---- main: 32 rows/block, 4 waves; wave w scans codes [w*256, w*256+256) ----
__global__ __launch_bounds__(256, 4) void vq_main(
    const float* __restrict__ x,
    const float* __restrict__ e,
    const unsigned short* __restrict__ eB,
    const float* __restrict__ e2h,
    float* __restrict__ out,
    float* __restrict__ loss)
{
  __shared__ float bestL[4 * RPB];
  __shared__ int   kL[4 * RPB];
  __shared__ int   kFin[RPB];
  __shared__ float x2s;

  const int t   = threadIdx.x;
  const int l   = t & 63;
  const int w   = t >> 6;
  const int col = l & 15;
  const int g   = l >> 4;
  const int B0  = blockIdx.x * RPB;

  // ---- burst-load x (8 independent float4), then split to fp16 (h,l) ----
  float4 xv[8];
  #pragma unroll
  for (int rt = 0; rt < 2; ++rt)
    #pragma unroll
    for (int kh = 0; kh < 2; ++kh) {
      const float* xp = x + (size_t)(B0 + rt * 16 + col) * DIM + kh * 32 + g * 8;
      xv[(rt * 2 + kh) * 2 + 0] = *(const float4*)xp;
      xv[(rt * 2 + kh) * 2 + 1] = *(const float4*)(xp + 4);
    }

  f16x8 a[2][2][2];     // [row-tile][k-half][h/l]
  float x2p = 0.f;
  #pragma unroll
  for (int rt = 0; rt < 2; ++rt)
    #pragma unroll
    for (int kh = 0; kh < 2; ++kh) {
      float4 v0 = xv[(rt * 2 + kh) * 2], v1 = xv[(rt * 2 + kh) * 2 + 1];
      float f[8] = {v0.x, v0.y, v0.z, v0.w, v1.x, v1.y, v1.z, v1.w};
      unsigned short hb[8], lb[8];
      #pragma unroll
      for (int j = 0; j < 8; ++j) {
        split2(f[j], hb[j], lb[j]);
        x2p = fmaf(f[j], f[j], x2p);
      }
      U4H uh; uh.u = pack8(hb); a[rt][kh][0] = uh.h;
      U4H ul; ul.u = pack8(lb); a[rt][kh][1] = ul.h;
    }
  // each wave covers all 32 rows x 64 dims exactly once -> full-wave reduce
  #pragma unroll
  for (int off = 1; off < 64; off <<= 1) x2p += __shfl_xor(x2p, off, 64);
  if (t == 0) x2s = x2p;

  float bestS[2][4];
  int   bestK[2][4];
  #pragma unroll
  for (int rt = 0; rt < 2; ++rt)
    #pragma unroll
    for (int r = 0; r < 4; ++r) { bestS[rt][r] = -3.402823466e38f; bestK[rt][r] = 0; }

  const unsigned short* ebase = eB + (size_t)w * 16 * 2048;
  const float* e2w = e2h + w * 256 + col;

  uint4 bA[4], bB[4];
  float e2A, e2B;
  #pragma unroll
  for (int q = 0; q < 4; ++q)
    bA[q] = *(const uint4*)(ebase + (size_t)q * 512 + l * 8);
  e2A = e2w[0];

  for (int ct = 0; ct < 16; ct += 2) {
    #pragma unroll
    for (int q = 0; q < 4; ++q)
      bB[q] = *(const uint4*)(ebase + (size_t)(ct + 1) * 2048 + (size_t)q * 512 + l * 8);
    e2B = e2w[(ct + 1) * 16];
    VQ_STEP(ct, bA, e2A);
    const int ctn = (ct + 2 < 16) ? ct + 2 : 14;   // tail reload, harmless
    #pragma unroll
    for (int q = 0; q < 4; ++q)
      bA[q] = *(const uint4*)(ebase + (size_t)ctn * 2048 + (size_t)q * 512 + l * 8);
    e2A = e2w[ctn * 16];
    VQ_STEP(ct + 1, bB, e2B);
  }

  // ---- intra-wave argmax(S') merge over the 16 code-columns ----
  #pragma unroll
  for (int off = 1; off <= 8; off <<= 1) {
    #pragma unroll
    for (int rt = 0; rt < 2; ++rt)
      #pragma unroll
      for (int r = 0; r < 4; ++r) {
        float sp = __shfl_xor(bestS[rt][r], off, 64);
        int   kp = __shfl_xor(bestK[rt][r], off, 64);
        if (sp > bestS[rt][r] || (sp == bestS[rt][r] && kp < bestK[rt][r])) {
          bestS[rt][r] = sp; bestK[rt][r] = kp;
        }
      }
  }
  if (col == 0) {
    #pragma unroll
    for (int rt = 0; rt < 2; ++rt)
      #pragma unroll
      for (int r = 0; r < 4; ++r) {
        const int row = rt * 16 + g * 4 + r;
        bestL[w * RPB + row] = bestS[rt][r];
        kL[w * RPB + row]    = bestK[rt][r];
      }
  }
  __syncthreads();

  // ---- cross-wave merge (ascending code ranges; strict > keeps lowest k) ----
  if (t < RPB) {
    float s = bestL[t]; int k = kL[t];
    #pragma unroll
    for (int w2 = 1; w2 < 4; ++w2) {
      float s2 = bestL[w2 * RPB + t]; int k2 = kL[w2 * RPB + t];
      if (s2 > s) { s = s2; k = k2; }
    }
    kFin[t] = k;
    float rs = s;
    #pragma unroll
    for (int off = 16; off > 0; off >>= 1) rs += __shfl_xor(rs, off, 64);
    if (t == 0)   // sum_d(block) = x2 - 2*Sum(S'best)
      atomicAdd(loss, fmaf(-2.f, rs, x2s) * (1.25f / (float)((size_t)NROWS * DIM)));
  }
  __syncthreads();

  // ---- cooperative gather-write of quantized rows (exact fp32 e copy) ----
  if (t < RPB * 4) {
    const int row = t >> 2, seg = t & 3;
    const int bk = kFin[row];
    const float4* src = (const float4*)(e + (size_t)bk * DIM + seg * 16);
    float4* dst = (float4*)(out + (size_t)(B0 + row) * DIM + seg * 16);
    #pragma unroll
    for (int i = 0; i < 4; ++i) dst[i] = src[i];
  }
}

extern "C" void kernel_launch(void* const* d_in, const int* in_sizes, int n_in,
                              void* d_out, int out_size, void* d_ws, size_t ws_size,
                              hipStream_t stream) {
  const float* x = (const float*)d_in[0];   // [65536, 64]
  const float* e = (const float*)d_in[1];   // [1024, 64]
  float* out  = (float*)d_out;              // quantized_st [65536*64] + loss [1]
  float* loss = out + (size_t)NROWS * DIM;

  unsigned short* eB = (unsigned short*)d_ws;            // 64 tiles * 2048 shorts = 256 KB
  float* e2h = (float*)((char*)d_ws + 64 * 2048 * 2);    // 4 KB

  vq_esplit<<<NCODE / 256, 256, 0, stream>>>(e, eB, e2h, loss);
  vq_main  <<<NBLK, 256, 0, stream>>>(x, e, eB, e2h, out, loss);
}

// Round 7
// 74.832 us; speedup vs baseline: 1.1768x; 1.1768x over previous
//
#include <hip/hip_runtime.h>

#define DIM   64
#define NROWS 65536
#define NCODE 1024
#define RPB   64
#define NBLK  (NROWS / RPB)       // 1024 blocks, 64 rows each

typedef float    f32x4 __attribute__((ext_vector_type(4)));
typedef _Float16 f16x8 __attribute__((ext_vector_type(8)));

union U4H { uint4 u; f16x8 h; };

// fp32 = h + r, h = RNE fp16; r exact (Sterbenz); l = RNE fp16 of r.
__device__ __forceinline__ void split2(float f, unsigned short& hb,
                                       unsigned short& lb) {
  _Float16 h = (_Float16)f;
  float r = f - (float)h;
  _Float16 lo = (_Float16)r;
  hb = __builtin_bit_cast(unsigned short, h);
  lb = __builtin_bit_cast(unsigned short, lo);
}
__device__ __forceinline__ uint4 pack8(const unsigned short* p) {
  return make_uint4((unsigned)p[0] | ((unsigned)p[1] << 16),
                    (unsigned)p[2] | ((unsigned)p[3] << 16),
                    (unsigned)p[4] | ((unsigned)p[5] << 16),
                    (unsigned)p[6] | ((unsigned)p[7] << 16));
}

// ---- pre-pass: e -> fp16 (h,l) B-fragments + e2/2; also zeroes loss ----
// tile gt (16 codes): 4 frags [kh0_h, kh0_l, kh1_h, kh1_l] x 512 shorts,
// each frag lane-linear: lane l owns shorts [l*8, l*8+8).
__global__ __launch_bounds__(256) void vq_esplit(const float* __restrict__ e,
                                                 unsigned short* __restrict__ eB,
                                                 float* __restrict__ e2h,
                                                 float* __restrict__ loss) {
  const int c = blockIdx.x * 256 + threadIdx.x;   // code 0..1023
  if (c == 0) *loss = 0.f;                        // stream-ordered before vq_main
  const int gt = c >> 4, cl = c & 15;
  float s = 0.f;
  #pragma unroll
  for (int kh = 0; kh < 2; ++kh) {
    #pragma unroll
    for (int g = 0; g < 4; ++g) {
      const float* ep = e + (size_t)c * DIM + kh * 32 + g * 8;
      float4 v0 = *(const float4*)ep;
      float4 v1 = *(const float4*)(ep + 4);
      float f[8] = {v0.x, v0.y, v0.z, v0.w, v1.x, v1.y, v1.z, v1.w};
      unsigned short hb[8], lb[8];
      #pragma unroll
      for (int j = 0; j < 8; ++j) {
        split2(f[j], hb[j], lb[j]);
        s = fmaf(f[j], f[j], s);
      }
      const size_t pos = (size_t)((g << 4) | cl) * 8;
      const size_t tb = (size_t)gt * 2048;
      *(uint4*)(eB + tb + (kh * 2 + 0) * 512 + pos) = pack8(hb);
      *(uint4*)(eB + tb + (kh * 2 + 1) * 512 + pos) = pack8(lb);
    }
  }
  e2h[c] = 0.5f * s;
}

// stage one 4 KB code-tile into LDS: 4 x global_load_lds_dwordx4 (1 KB each).
// LDS dest = uniform base + lane*16; global src = base + lane*16 (lane-linear
// frag layout matches the HW write pattern exactly).
__device__ __forceinline__ void stage4(const unsigned short* src,
                                       unsigned short* dst, int l) {
  #pragma unroll
  for (int q = 0; q < 4; ++q)
    __builtin_amdgcn_global_load_lds(
        (const __attribute__((address_space(1))) unsigned int*)
            (unsigned long long)(src + q * 512 + (size_t)l * 8),
        (__attribute__((address_space(3))) unsigned int*)
            (unsigned long long)(dst + q * 512),
        16, 0, 0);
}

#define STAGE(CT) stage4(ebase + (size_t)(CT) * 2048, ldsW + ((CT) & 3) * 2048, l)

// S' = dot(x,e) - e2/2 as one MFMA chain seeded with C = -e2/2.
#define TILE_BODY(CT)                                                              \
  {                                                                                \
    const unsigned short* sl = ldsW + ((CT) & 3) * 2048;                           \
    uint4 u0 = *(const uint4*)(sl + 0 * 512 + l * 8);                              \
    uint4 u1 = *(const uint4*)(sl + 1 * 512 + l * 8);                              \
    uint4 u2 = *(const uint4*)(sl + 2 * 512 + l * 8);                              \
    uint4 u3 = *(const uint4*)(sl + 3 * 512 + l * 8);                              \
    U4H q0, q1, q2, q3; q0.u = u0; q1.u = u1; q2.u = u2; q3.u = u3;                \
    f16x8 b0h = q0.h, b0l = q1.h, b1h = q2.h, b1l = q3.h;                          \
    const float ne2 = -e2v[CT];                                                    \
    const int kk0 = wv * 256 + (CT) * 16 + col;                                    \
    _Pragma("unroll")                                                              \
    for (int rt = 0; rt < 4; ++rt) {                                               \
      f32x4 c = {ne2, ne2, ne2, ne2};                                              \
      c = __builtin_amdgcn_mfma_f32_16x16x32_f16(a[rt][0][0], b0h, c, 0, 0, 0);    \
      c = __builtin_amdgcn_mfma_f32_16x16x32_f16(a[rt][0][1], b0h, c, 0, 0, 0);    \
      c = __builtin_amdgcn_mfma_f32_16x16x32_f16(a[rt][0][0], b0l, c, 0, 0, 0);    \
      c = __builtin_amdgcn_mfma_f32_16x16x32_f16(a[rt][1][0], b1h, c, 0, 0, 0);    \
      c = __builtin_amdgcn_mfma_f32_16x16x32_f16(a[rt][1][1], b1h, c, 0, 0, 0);    \
      c = __builtin_amdgcn_mfma_f32_16x16x32_f16(a[rt][1][0], b1l, c, 0, 0, 0);    \
      _Pragma("unroll")                                                            \
      for (int r = 0; r < 4; ++r) {                                                \
        if (c[r] > bestS[rt][r]) { bestS[rt][r] = c[r]; bestK[rt][r] = kk0; }      \
      }                                                                            \
    }                                                                              \
  }

#define STEP(CT, VM)                                                               \
  do {                                                                             \
    if ((CT) + 3 < 16) STAGE((CT) + 3);                                            \
    asm volatile("s_waitcnt vmcnt(" #VM ")" ::: "memory");                         \
    TILE_BODY(CT);                                                                 \
  } while (0)

// ---- main: 64 rows/block, 4 waves; wave wv scans codes [wv*256, wv*256+256) ----
__global__ __launch_bounds__(256) void vq_main(
    const float* __restrict__ x,
    const float* __restrict__ e,
    const unsigned short* __restrict__ eB,
    const float* __restrict__ e2h,
    float* __restrict__ out,
    float* __restrict__ loss)
{
  __shared__ __align__(16) unsigned short ldsB[4][4 * 2048];  // 64 KB ring, 4 waves
  __shared__ float bestL[256];
  __shared__ int   kL[256];
  __shared__ int   kFin[64];

  const int t   = threadIdx.x;
  const int l   = t & 63;
  const int wv  = t >> 6;
  const int col = l & 15;
  const int g   = l >> 4;
  const int B0  = blockIdx.x * RPB;

  unsigned short* ldsW = &ldsB[wv][0];
  const unsigned short* ebase = eB + (size_t)wv * 16 * 2048;

  // issue first 3 tile stages immediately (12 KB in flight, no VGPR cost)
  STAGE(0); STAGE(1); STAGE(2);

  // ---- x -> fp16 (h,l) A-fragments in registers + Sum(x^2) ----
  f16x8 a[4][2][2];     // [row-tile][k-half][h/l]
  float x2p = 0.f;
  #pragma unroll
  for (int rt = 0; rt < 4; ++rt)
    #pragma unroll
    for (int kh = 0; kh < 2; ++kh) {
      const float* xp = x + (size_t)(B0 + rt * 16 + col) * DIM + kh * 32 + g * 8;
      float4 v0 = *(const float4*)xp;
      float4 v1 = *(const float4*)(xp + 4);
      float f[8] = {v0.x, v0.y, v0.z, v0.w, v1.x, v1.y, v1.z, v1.w};
      unsigned short hb[8], lb[8];
      #pragma unroll
      for (int j = 0; j < 8; ++j) {
        split2(f[j], hb[j], lb[j]);
        x2p = fmaf(f[j], f[j], x2p);
      }
      U4H uh; uh.u = pack8(hb); a[rt][kh][0] = uh.h;
      U4H ul; ul.u = pack8(lb); a[rt][kh][1] = ul.h;
    }
  // each wave covers all 64 rows x 64 dims exactly once -> full-wave reduce
  #pragma unroll
  for (int off = 1; off < 64; off <<= 1) x2p += __shfl_xor(x2p, off, 64);

  // per-code-column e2/2 for this wave's 16 tiles
  const float* e2w = e2h + wv * 256 + col;
  float e2v[16];
  #pragma unroll
  for (int ct = 0; ct < 16; ++ct) e2v[ct] = e2w[ct * 16];

  float bestS[4][4];
  int   bestK[4][4];
  #pragma unroll
  for (int rt = 0; rt < 4; ++rt)
    #pragma unroll
    for (int r = 0; r < 4; ++r) { bestS[rt][r] = -3.402823466e38f; bestK[rt][r] = 0; }

  // drain: tiles 0-2 resident in LDS; x/e2 reg-deps compiler-handled anyway
  asm volatile("s_waitcnt vmcnt(0)" ::: "memory");

  STEP( 0, 12); STEP( 1, 12); STEP( 2, 12); STEP( 3, 12);
  STEP( 4, 12); STEP( 5, 12); STEP( 6, 12); STEP( 7, 12);
  STEP( 8, 12); STEP( 9, 12); STEP(10, 12); STEP(11, 12);
  STEP(12, 12); STEP(13,  8); STEP(14,  4); STEP(15,  0);

  // ---- intra-wave argmax(S') merge over the 16 code-columns ----
  #pragma unroll
  for (int off = 1; off <= 8; off <<= 1) {
    #pragma unroll
    for (int rt = 0; rt < 4; ++rt)
      #pragma unroll
      for (int r = 0; r < 4; ++r) {
        float sp = __shfl_xor(bestS[rt][r], off, 64);
        int   kp = __shfl_xor(bestK[rt][r], off, 64);
        if (sp > bestS[rt][r] || (sp == bestS[rt][r] && kp < bestK[rt][r])) {
          bestS[rt][r] = sp; bestK[rt][r] = kp;
        }
      }
  }
  if (col == 0) {
    #pragma unroll
    for (int rt = 0; rt < 4; ++rt)
      #pragma unroll
      for (int r = 0; r < 4; ++r) {
        const int row = rt * 16 + g * 4 + r;
        bestL[wv * RPB + row] = bestS[rt][r];
        kL[wv * RPB + row]    = bestK[rt][r];
      }
  }
  __syncthreads();

  // ---- cross-wave merge (ascending code ranges; strict > keeps lowest k) ----
  if (t < RPB) {
    float s = bestL[t]; int k = kL[t];
    #pragma unroll
    for (int w2 = 1; w2 < 4; ++w2) {
      float s2 = bestL[w2 * RPB + t]; int k2 = kL[w2 * RPB + t];
      if (s2 > s) { s = s2; k = k2; }
    }
    kFin[t] = k;
    float rs = s;
    #pragma unroll
    for (int off = 1; off < 64; off <<= 1) rs += __shfl_xor(rs, off, 64);
    if (t == 0)   // sum_d(block) = x2 - 2*Sum(S'best)
      atomicAdd(loss, fmaf(-2.f, rs, x2p) * (1.25f / (float)((size_t)NROWS * DIM)));
  }
  __syncthreads();

  // ---- cooperative gather-write of quantized rows (exact fp32 e copy) ----
  {
    const int row = t >> 2, seg = t & 3;
    const int bk = kFin[row];
    const float4* src = (const float4*)(e + (size_t)bk * DIM + seg * 16);
    float4* dst = (float4*)(out + (size_t)(B0 + row) * DIM + seg * 16);
    #pragma unroll
    for (int i = 0; i < 4; ++i) dst[i] = src[i];
  }
}

extern "C" void kernel_launch(void* const* d_in, const int* in_sizes, int n_in,
                              void* d_out, int out_size, void* d_ws, size_t ws_size,
                              hipStream_t stream) {
  const float* x = (const float*)d_in[0];   // [65536, 64]
  const float* e = (const float*)d_in[1];   // [1024, 64]
  float* out  = (float*)d_out;              // quantized_st [65536*64] + loss [1]
  float* loss = out + (size_t)NROWS * DIM;

  unsigned short* eB = (unsigned short*)d_ws;            // 64 tiles * 4 KB = 256 KB
  float* e2h = (float*)((char*)d_ws + 64 * 2048 * 2);    // 4 KB

  vq_esplit<<<NCODE / 256, 256, 0, stream>>>(e, eB, e2h, loss);
  vq_main  <<<NBLK, 256, 0, stream>>>(x, e, eB, e2h, out, loss);
}

// Round 8
// 63.946 us; speedup vs baseline: 1.3771x; 1.1702x over previous
//
#include <hip/hip_runtime.h>

#define DIM   64
#define NROWS 65536
#define NCODE 1024
#define RPB   128
#define NBLK  (NROWS / RPB)       // 512 blocks -> 2 blocks/CU, 8 waves/CU

typedef float    f32x4 __attribute__((ext_vector_type(4)));
typedef _Float16 f16x8 __attribute__((ext_vector_type(8)));

union U4H { uint4 u; f16x8 h; };

// fp32 = h + r, h = RNE fp16; r exact (Sterbenz); l = RNE fp16 of r.
__device__ __forceinline__ void split2(float f, unsigned short& hb,
                                       unsigned short& lb) {
  _Float16 h = (_Float16)f;
  float r = f - (float)h;
  _Float16 lo = (_Float16)r;
  hb = __builtin_bit_cast(unsigned short, h);
  lb = __builtin_bit_cast(unsigned short, lo);
}
__device__ __forceinline__ uint4 pack8(const unsigned short* p) {
  return make_uint4((unsigned)p[0] | ((unsigned)p[1] << 16),
                    (unsigned)p[2] | ((unsigned)p[3] << 16),
                    (unsigned)p[4] | ((unsigned)p[5] << 16),
                    (unsigned)p[6] | ((unsigned)p[7] << 16));
}

// ---- pre-pass: e -> fp16 (h,l) B-fragments + e2/2; also zeroes loss ----
// tile gt (16 codes): 4 frags [kh0_h, kh0_l, kh1_h, kh1_l] x 512 shorts,
// each frag lane-linear: lane l owns shorts [l*8, l*8+8).
__global__ __launch_bounds__(256) void vq_esplit(const float* __restrict__ e,
                                                 unsigned short* __restrict__ eB,
                                                 float* __restrict__ e2h,
                                                 float* __restrict__ loss) {
  const int c = blockIdx.x * 256 + threadIdx.x;   // code 0..1023
  if (c == 0) *loss = 0.f;                        // stream-ordered before vq_main
  const int gt = c >> 4, cl = c & 15;
  float s = 0.f;
  #pragma unroll
  for (int kh = 0; kh < 2; ++kh) {
    #pragma unroll
    for (int g = 0; g < 4; ++g) {
      const float* ep = e + (size_t)c * DIM + kh * 32 + g * 8;
      float4 v0 = *(const float4*)ep;
      float4 v1 = *(const float4*)(ep + 4);
      float f[8] = {v0.x, v0.y, v0.z, v0.w, v1.x, v1.y, v1.z, v1.w};
      unsigned short hb[8], lb[8];
      #pragma unroll
      for (int j = 0; j < 8; ++j) {
        split2(f[j], hb[j], lb[j]);
        s = fmaf(f[j], f[j], s);
      }
      const size_t pos = (size_t)((g << 4) | cl) * 8;
      const size_t tb = (size_t)gt * 2048;
      *(uint4*)(eB + tb + (kh * 2 + 0) * 512 + pos) = pack8(hb);
      *(uint4*)(eB + tb + (kh * 2 + 1) * 512 + pos) = pack8(lb);
    }
  }
  e2h[c] = 0.5f * s;
}

// one 16B-per-lane async global->LDS copy (1 KB per wave-instruction)
__device__ __forceinline__ void load_lds16(const void* gsrc, void* ldst) {
  __builtin_amdgcn_global_load_lds(
      (const __attribute__((address_space(1))) unsigned int*)
          (unsigned long long)gsrc,
      (__attribute__((address_space(3))) unsigned int*)
          (unsigned long long)ldst,
      16, 0, 0);
}

// ---- main: 128 rows/block, 4 waves x 32 rows; ALL waves scan ALL codes
// from a block-shared 4-deep LDS tile ring. 1 stage instr/wave/step. ----
__global__ __launch_bounds__(256) void vq_main(
    const float* __restrict__ x,
    const float* __restrict__ e,
    const unsigned short* __restrict__ eB,
    const float* __restrict__ e2h,
    float* __restrict__ out,
    float* __restrict__ loss)
{
  __shared__ __align__(16) unsigned short tiles[4 * 2048];  // 16 KB ring
  __shared__ __align__(16) float e2L[NCODE];                // 4 KB
  __shared__ int kFin[RPB];

  const int t   = threadIdx.x;
  const int l   = t & 63;
  const int wv  = t >> 6;
  const int col = l & 15;
  const int g   = l >> 4;
  const int B0  = blockIdx.x * RPB;
  const int R0  = B0 + wv * 32;          // this wave's 32 rows

  // ---- x loads FIRST (their waits leave the later stage-loads in flight) ----
  float4 xv[8];
  #pragma unroll
  for (int rt = 0; rt < 2; ++rt)
    #pragma unroll
    for (int kh = 0; kh < 2; ++kh) {
      const float* xp = x + (size_t)(R0 + rt * 16 + col) * DIM + kh * 32 + g * 8;
      xv[(rt * 2 + kh) * 2 + 0] = *(const float4*)xp;
      xv[(rt * 2 + kh) * 2 + 1] = *(const float4*)(xp + 4);
    }

  // ---- async stages: e2 (4 KB once) + tiles 0..2 ----
#define STAGE(CT) load_lds16(eB + (size_t)(CT) * 2048 + wv * 512 + l * 8, \
                             tiles + ((CT) & 3) * 2048 + wv * 512)
  load_lds16(e2h + wv * 256 + l * 4, e2L + wv * 256);
  STAGE(0); STAGE(1); STAGE(2);

  // ---- split x -> fp16 (h,l) A-frags + Sum(x^2) over this wave's rows ----
  f16x8 a[2][2][2];     // [row-tile][k-half][h/l]
  float x2p = 0.f;
  #pragma unroll
  for (int rt = 0; rt < 2; ++rt)
    #pragma unroll
    for (int kh = 0; kh < 2; ++kh) {
      float4 v0 = xv[(rt * 2 + kh) * 2], v1 = xv[(rt * 2 + kh) * 2 + 1];
      float f[8] = {v0.x, v0.y, v0.z, v0.w, v1.x, v1.y, v1.z, v1.w};
      unsigned short hb[8], lb[8];
      #pragma unroll
      for (int j = 0; j < 8; ++j) {
        split2(f[j], hb[j], lb[j]);
        x2p = fmaf(f[j], f[j], x2p);
      }
      U4H uh; uh.u = pack8(hb); a[rt][kh][0] = uh.h;
      U4H ul; ul.u = pack8(lb); a[rt][kh][1] = ul.h;
    }
  #pragma unroll
  for (int off = 1; off < 64; off <<= 1) x2p += __shfl_xor(x2p, off, 64);

  float bestS[2][4];
  int   bestK[2][4];
  #pragma unroll
  for (int rt = 0; rt < 2; ++rt)
    #pragma unroll
    for (int r = 0; r < 4; ++r) { bestS[rt][r] = -3.402823466e38f; bestK[rt][r] = 0; }

#define VMWAIT(N)                                              \
  do {                                                         \
    asm volatile("s_waitcnt vmcnt(" #N ")" ::: "memory");      \
    __builtin_amdgcn_sched_barrier(0);                         \
  } while (0)

#define TILE(CT)                                                                   \
  do {                                                                             \
    const unsigned short* sl = tiles + ((CT) & 3) * 2048;                          \
    uint4 u0 = *(const uint4*)(sl + 0 * 512 + l * 8);                              \
    uint4 u1 = *(const uint4*)(sl + 1 * 512 + l * 8);                              \
    uint4 u2 = *(const uint4*)(sl + 2 * 512 + l * 8);                              \
    uint4 u3 = *(const uint4*)(sl + 3 * 512 + l * 8);                              \
    const float ne2 = -e2L[(CT) * 16 + col];                                       \
    U4H q0, q1, q2, q3; q0.u = u0; q1.u = u1; q2.u = u2; q3.u = u3;                \
    const int kk0 = (CT) * 16 + col;                                               \
    _Pragma("unroll")                                                              \
    for (int rt = 0; rt < 2; ++rt) {                                               \
      f32x4 c = {ne2, ne2, ne2, ne2};                                              \
      c = __builtin_amdgcn_mfma_f32_16x16x32_f16(a[rt][0][0], q0.h, c, 0, 0, 0);   \
      c = __builtin_amdgcn_mfma_f32_16x16x32_f16(a[rt][0][1], q0.h, c, 0, 0, 0);   \
      c = __builtin_amdgcn_mfma_f32_16x16x32_f16(a[rt][0][0], q1.h, c, 0, 0, 0);   \
      c = __builtin_amdgcn_mfma_f32_16x16x32_f16(a[rt][1][0], q2.h, c, 0, 0, 0);   \
      c = __builtin_amdgcn_mfma_f32_16x16x32_f16(a[rt][1][1], q2.h, c, 0, 0, 0);   \
      c = __builtin_amdgcn_mfma_f32_16x16x32_f16(a[rt][1][0], q3.h, c, 0, 0, 0);   \
      _Pragma("unroll")                                                            \
      for (int r = 0; r < 4; ++r) {                                                \
        if (c[r] > bestS[rt][r]) { bestS[rt][r] = c[r]; bestK[rt][r] = kk0; }      \
      }                                                                            \
    }                                                                              \
  } while (0)

  // steady state: wait own chunk of tile ct (vmcnt(2) leaves ct+1, ct+2 in
  // flight), barrier (=> ALL waves' chunks of ct landed), compute, stage ct+3.
  // Ring slot (ct+3)&3 was read at step ct-1, two barriers ago -> safe.
  #pragma unroll 1
  for (int ct = 0; ct < 61; ++ct) {
    VMWAIT(2);
    __builtin_amdgcn_s_barrier();
    TILE(ct);
    STAGE(ct + 3);
  }
  VMWAIT(2); __builtin_amdgcn_s_barrier(); TILE(61);
  VMWAIT(1); __builtin_amdgcn_s_barrier(); TILE(62);
  VMWAIT(0); __builtin_amdgcn_s_barrier(); TILE(63);

  // ---- intra-wave argmax(S') merge over the 16 code-columns ----
  #pragma unroll
  for (int off = 1; off <= 8; off <<= 1) {
    #pragma unroll
    for (int rt = 0; rt < 2; ++rt)
      #pragma unroll
      for (int r = 0; r < 4; ++r) {
        float sp = __shfl_xor(bestS[rt][r], off, 64);
        int   kp = __shfl_xor(bestK[rt][r], off, 64);
        if (sp > bestS[rt][r] || (sp == bestS[rt][r] && kp < bestK[rt][r])) {
          bestS[rt][r] = sp; bestK[rt][r] = kp;
        }
      }
  }

  // lanes col==0 (g=0..3) hold final minima for rows wv*32 + rt*16 + g*4 + r
  float ssum = 0.f;
  if (col == 0) {
    #pragma unroll
    for (int rt = 0; rt < 2; ++rt)
      #pragma unroll
      for (int r = 0; r < 4; ++r) {
        kFin[wv * 32 + rt * 16 + g * 4 + r] = bestK[rt][r];
        ssum += bestS[rt][r];
      }
  }
  ssum += __shfl_xor(ssum, 16, 64);
  ssum += __shfl_xor(ssum, 32, 64);
  if (l == 0)   // wave's 32-row loss partial: Sum d = Sum x^2 - 2*Sum S'best
    atomicAdd(loss, fmaf(-2.f, ssum, x2p) * (1.25f / (float)((size_t)NROWS * DIM)));

  __syncthreads();   // kFin visible (vmcnt already drained)

  // ---- cooperative gather-write: 2 threads/row, 32 floats each ----
  {
    const int row = t >> 1, half = t & 1;
    const int bk = kFin[row];
    const float4* src = (const float4*)(e + (size_t)bk * DIM + half * 32);
    float4* dst = (float4*)(out + (size_t)(B0 + row) * DIM + half * 32);
    #pragma unroll
    for (int i = 0; i < 8; ++i) dst[i] = src[i];
  }
}

extern "C" void kernel_launch(void* const* d_in, const int* in_sizes, int n_in,
                              void* d_out, int out_size, void* d_ws, size_t ws_size,
                              hipStream_t stream) {
  const float* x = (const float*)d_in[0];   // [65536, 64]
  const float* e = (const float*)d_in[1];   // [1024, 64]
  float* out  = (float*)d_out;              // quantized_st [65536*64] + loss [1]
  float* loss = out + (size_t)NROWS * DIM;

  unsigned short* eB = (unsigned short*)d_ws;            // 64 tiles * 4 KB = 256 KB
  float* e2h = (float*)((char*)d_ws + 64 * 2048 * 2);    // 4 KB

  vq_esplit<<<NCODE / 256, 256, 0, stream>>>(e, eB, e2h, loss);
  vq_main  <<<NBLK, 256, 0, stream>>>(x, e, eB, e2h, out, loss);
}

// Round 9
// 47.784 us; speedup vs baseline: 1.8429x; 1.3382x over previous
//
#include <hip/hip_runtime.h>

#define DIM   64
#define NROWS 65536
#define NCODE 1024
#define RPB   128
#define NBLK  (NROWS / RPB)       // 512 blocks x 512 thr -> 2 blocks/CU, 16 waves/CU

typedef float    f32x4 __attribute__((ext_vector_type(4)));
typedef _Float16 f16x8 __attribute__((ext_vector_type(8)));

union U4H { uint4 u; f16x8 h; };

// fp32 = h + r, h = RNE fp16; r exact (Sterbenz); l = RNE fp16 of r.
__device__ __forceinline__ void split2(float f, unsigned short& hb,
                                       unsigned short& lb) {
  _Float16 h = (_Float16)f;
  float r = f - (float)h;
  _Float16 lo = (_Float16)r;
  hb = __builtin_bit_cast(unsigned short, h);
  lb = __builtin_bit_cast(unsigned short, lo);
}
__device__ __forceinline__ uint4 pack8(const unsigned short* p) {
  return make_uint4((unsigned)p[0] | ((unsigned)p[1] << 16),
                    (unsigned)p[2] | ((unsigned)p[3] << 16),
                    (unsigned)p[4] | ((unsigned)p[5] << 16),
                    (unsigned)p[6] | ((unsigned)p[7] << 16));
}

// ---- pre-pass: e -> fp16 (h,l) B-fragments + e2/2; also zeroes loss ----
// tile gt (16 codes): 4 frags [kh0_h, kh0_l, kh1_h, kh1_l] x 512 shorts,
// each frag lane-linear: lane l owns shorts [l*8, l*8+8).
__global__ __launch_bounds__(256) void vq_esplit(const float* __restrict__ e,
                                                 unsigned short* __restrict__ eB,
                                                 float* __restrict__ e2h,
                                                 float* __restrict__ loss) {
  const int c = blockIdx.x * 256 + threadIdx.x;   // code 0..1023
  if (c == 0) *loss = 0.f;                        // stream-ordered before vq_main
  const int gt = c >> 4, cl = c & 15;
  float s = 0.f;
  #pragma unroll
  for (int kh = 0; kh < 2; ++kh) {
    #pragma unroll
    for (int g = 0; g < 4; ++g) {
      const float* ep = e + (size_t)c * DIM + kh * 32 + g * 8;
      float4 v0 = *(const float4*)ep;
      float4 v1 = *(const float4*)(ep + 4);
      float f[8] = {v0.x, v0.y, v0.z, v0.w, v1.x, v1.y, v1.z, v1.w};
      unsigned short hb[8], lb[8];
      #pragma unroll
      for (int j = 0; j < 8; ++j) {
        split2(f[j], hb[j], lb[j]);
        s = fmaf(f[j], f[j], s);
      }
      const size_t pos = (size_t)((g << 4) | cl) * 8;
      const size_t tb = (size_t)gt * 2048;
      *(uint4*)(eB + tb + (kh * 2 + 0) * 512 + pos) = pack8(hb);
      *(uint4*)(eB + tb + (kh * 2 + 1) * 512 + pos) = pack8(lb);
    }
  }
  e2h[c] = 0.5f * s;
}

// one 16B-per-lane async global->LDS copy (1 KB per wave-instruction)
__device__ __forceinline__ void load_lds16(const void* gsrc, void* ldst) {
  __builtin_amdgcn_global_load_lds(
      (const __attribute__((address_space(1))) unsigned int*)
          (unsigned long long)gsrc,
      (__attribute__((address_space(3))) unsigned int*)
          (unsigned long long)ldst,
      16, 0, 0);
}

// ---- main: 128 rows/block, 8 waves x 16 rows; all waves scan all 1024 codes
// from a block-shared 8-deep LDS tile ring, phase-rotated per block. ----
__global__ __launch_bounds__(512) void vq_main(
    const float* __restrict__ x,
    const float* __restrict__ e,
    const unsigned short* __restrict__ eB,
    const float* __restrict__ e2h,
    float* __restrict__ out,
    float* __restrict__ loss)
{
  __shared__ __align__(16) unsigned short tiles[8 * 2048];  // 32 KB ring
  __shared__ __align__(16) float e2L[NCODE];                // 4 KB
  __shared__ int   kFin[RPB];
  __shared__ float lossP[8];

  const int t     = threadIdx.x;
  const int l     = t & 63;
  const int wv    = t >> 6;
  const int col   = l & 15;
  const int g     = l >> 4;
  const int B0    = blockIdx.x * RPB;
  const int R0    = B0 + wv * 16;                    // this wave's 16 rows
  const int phase = (blockIdx.x * 23) & 63;          // decorrelate L2 streams

  // ---- x loads first (oldest vmem; consumed in prologue) ----
  float4 xv[4];
  #pragma unroll
  for (int kh = 0; kh < 2; ++kh) {
    const float* xp = x + (size_t)(R0 + col) * DIM + kh * 32 + g * 8;
    xv[kh * 2 + 0] = *(const float4*)xp;
    xv[kh * 2 + 1] = *(const float4*)(xp + 4);
  }

  // ---- async stages: e2 (4 KB once) + tiles 0..5 (depth 6) ----
#define STAGE(CTL)                                                        \
  do {                                                                    \
    if (wv < 4) {                                                         \
      const int pt_ = (phase + (CTL)) & 63;                               \
      load_lds16(eB + (size_t)pt_ * 2048 + wv * 512 + l * 8,              \
                 tiles + ((CTL) & 7) * 2048 + wv * 512);                  \
    }                                                                     \
  } while (0)

  if (wv < 4) load_lds16(e2h + wv * 256 + l * 4, e2L + wv * 256);
  STAGE(0); STAGE(1); STAGE(2); STAGE(3); STAGE(4); STAGE(5);

  // ---- split x -> fp16 (h,l) A-frags + Sum(x^2) over this wave's 16 rows ----
  f16x8 a[2][2];     // [k-half][h/l]
  float x2p = 0.f;
  #pragma unroll
  for (int kh = 0; kh < 2; ++kh) {
    float4 v0 = xv[kh * 2], v1 = xv[kh * 2 + 1];
    float f[8] = {v0.x, v0.y, v0.z, v0.w, v1.x, v1.y, v1.z, v1.w};
    unsigned short hb[8], lb[8];
    #pragma unroll
    for (int j = 0; j < 8; ++j) {
      split2(f[j], hb[j], lb[j]);
      x2p = fmaf(f[j], f[j], x2p);
    }
    U4H uh; uh.u = pack8(hb); a[kh][0] = uh.h;
    U4H ul; ul.u = pack8(lb); a[kh][1] = ul.h;
  }
  #pragma unroll
  for (int off = 1; off < 64; off <<= 1) x2p += __shfl_xor(x2p, off, 64);

  float bestS[4];
  int   bestK[4];
  #pragma unroll
  for (int r = 0; r < 4; ++r) { bestS[r] = -3.402823466e38f; bestK[r] = 0x7FFFFFFF; }

#define VMWAIT(N)                                              \
  do {                                                         \
    asm volatile("s_waitcnt vmcnt(" #N ")" ::: "memory");      \
    __builtin_amdgcn_sched_barrier(0);                         \
  } while (0)

  // steady state, ct = 0..63 uniform (wrap-staging, no tail special case):
  //   VMWAIT(5): own chunk of tile ct landed (6 stage-loads in flight max)
  //   barrier  : all 4 staging waves' chunks of ct landed -> tile complete
  //   compute tile ct, stage ct+6 into slot (ct+6)&7 (= slot of ct-2,
  //   whose reads were lgkm-consumed before 2 barriers ago -> safe)
  #pragma unroll 1
  for (int ct = 0; ct < 64; ++ct) {
    VMWAIT(5);
    __builtin_amdgcn_s_barrier();
    {
      const int pt = (phase + ct) & 63;
      const unsigned short* sl = tiles + (ct & 7) * 2048;
      uint4 u0 = *(const uint4*)(sl + 0 * 512 + l * 8);
      uint4 u1 = *(const uint4*)(sl + 1 * 512 + l * 8);
      uint4 u2 = *(const uint4*)(sl + 2 * 512 + l * 8);
      uint4 u3 = *(const uint4*)(sl + 3 * 512 + l * 8);
      const float ne2 = -e2L[pt * 16 + col];
      U4H q0, q1, q2, q3; q0.u = u0; q1.u = u1; q2.u = u2; q3.u = u3;
      const int kk0 = pt * 16 + col;
      // two independent 3-chains (halved dependent latency), then add
      f32x4 c0 = {ne2, ne2, ne2, ne2};
      f32x4 c1 = {0.f, 0.f, 0.f, 0.f};
      c0 = __builtin_amdgcn_mfma_f32_16x16x32_f16(a[0][0], q0.h, c0, 0, 0, 0);
      c1 = __builtin_amdgcn_mfma_f32_16x16x32_f16(a[1][0], q2.h, c1, 0, 0, 0);
      c0 = __builtin_amdgcn_mfma_f32_16x16x32_f16(a[0][1], q0.h, c0, 0, 0, 0);
      c1 = __builtin_amdgcn_mfma_f32_16x16x32_f16(a[1][1], q2.h, c1, 0, 0, 0);
      c0 = __builtin_amdgcn_mfma_f32_16x16x32_f16(a[0][0], q1.h, c0, 0, 0, 0);
      c1 = __builtin_amdgcn_mfma_f32_16x16x32_f16(a[1][0], q3.h, c1, 0, 0, 0);
      #pragma unroll
      for (int r = 0; r < 4; ++r) {
        float sv = c0[r] + c1[r];
        // lexicographic (S' desc, k asc): scan-order-invariant argmin
        bool take = (sv > bestS[r]) || (sv == bestS[r] && kk0 < bestK[r]);
        if (take) { bestS[r] = sv; bestK[r] = kk0; }
      }
    }
    STAGE(ct + 6);
  }

  // ---- intra-wave argmax(S') merge over the 16 code-columns ----
  #pragma unroll
  for (int off = 1; off <= 8; off <<= 1) {
    #pragma unroll
    for (int r = 0; r < 4; ++r) {
      float sp = __shfl_xor(bestS[r], off, 64);
      int   kp = __shfl_xor(bestK[r], off, 64);
      if (sp > bestS[r] || (sp == bestS[r] && kp < bestK[r])) {
        bestS[r] = sp; bestK[r] = kp;
      }
    }
  }

  // lanes col==0 (g=0..3) hold final minima for rows R0 + g*4 + r
  float ssum = 0.f;
  if (col == 0) {
    #pragma unroll
    for (int r = 0; r < 4; ++r) {
      kFin[wv * 16 + g * 4 + r] = bestK[r];
      ssum += bestS[r];
    }
  }
  ssum += __shfl_xor(ssum, 16, 64);
  ssum += __shfl_xor(ssum, 32, 64);
  if (l == 0)   // wave partial: Sum d(16 rows) = Sum x^2 - 2*Sum S'best
    lossP[wv] = fmaf(-2.f, ssum, x2p);

  __syncthreads();
  if (t == 0) {
    float bl = 0.f;
    #pragma unroll
    for (int i = 0; i < 8; ++i) bl += lossP[i];
    atomicAdd(loss, bl * (1.25f / (float)((size_t)NROWS * DIM)));
  }

  // ---- cooperative gather-write: 4 threads/row, 16 floats each ----
  {
    const int row = t >> 2, seg = t & 3;
    const int bk = kFin[row];
    const float4* src = (const float4*)(e + (size_t)bk * DIM + seg * 16);
    float4* dst = (float4*)(out + (size_t)(B0 + row) * DIM + seg * 16);
    #pragma unroll
    for (int i = 0; i < 4; ++i) dst[i] = src[i];
  }
}

extern "C" void kernel_launch(void* const* d_in, const int* in_sizes, int n_in,
                              void* d_out, int out_size, void* d_ws, size_t ws_size,
                              hipStream_t stream) {
  const float* x = (const float*)d_in[0];   // [65536, 64]
  const float* e = (const float*)d_in[1];   // [1024, 64]
  float* out  = (float*)d_out;              // quantized_st [65536*64] + loss [1]
  float* loss = out + (size_t)NROWS * DIM;

  unsigned short* eB = (unsigned short*)d_ws;            // 64 tiles * 4 KB = 256 KB
  float* e2h = (float*)((char*)d_ws + 64 * 2048 * 2);    // 4 KB

  vq_esplit<<<NCODE / 256, 256, 0, stream>>>(e, eB, e2h, loss);
  vq_main  <<<NBLK, 512, 0, stream>>>(x, e, eB, e2h, out, loss);
}